// Round 3
// baseline (163773.938 us; speedup 1.0000x reference)
//
#include <hip/hip_runtime.h>

namespace {
constexpr int B = 128;      // batch
constexpr int D = 80;       // mel dim
constexpr int H = 256;      // hidden
constexpr int PP = 128;     // prenet out
constexpr int TIN = 512;    // encoder steps
constexpr int RSTEPS = 200; // reduced steps
constexpr int RF = 5;       // reduction factor
constexpr int H3 = 3 * H;   // 768
constexpr int GRID = 512;   // persistent blocks (2 per CU)
constexpr int NTHR = 512;   // 8 waves
}

__device__ __forceinline__ float sigm(float x) { return 1.f / (1.f + __expf(-x)); }
__device__ __forceinline__ float tanh_(float x) { return 1.f - 2.f / (__expf(2.f * x) + 1.f); }

// ---------------------------------------------------------------------------
// grid barrier: monotonic counter, agent-scope acq/rel (cross-XCD safe)
__device__ __forceinline__ void gbar(unsigned* cnt, unsigned& n) {
  __syncthreads();
  if (threadIdx.x == 0) {
    n += 1;
    __hip_atomic_fetch_add(cnt, 1u, __ATOMIC_ACQ_REL, __HIP_MEMORY_SCOPE_AGENT);
    const unsigned tgt = n * (unsigned)GRID;
    while (__hip_atomic_load(cnt, __ATOMIC_ACQUIRE, __HIP_MEMORY_SCOPE_AGENT) < tgt)
      __builtin_amdgcn_s_sleep(8);
  }
  __syncthreads();
}

// ---------------------------------------------------------------------------
// keys[t,b,k] = sum_h memory[t,b,h] * Wm[h,k]
__global__ __launch_bounds__(256) void k_keys(const float* __restrict__ mem,
                                              const float* __restrict__ Wm,
                                              float* __restrict__ keys) {
  const int k = threadIdx.x;
  const int m0 = blockIdx.x * 32;
  const float* xb = mem + (size_t)m0 * H;
  float acc[32];
#pragma unroll
  for (int i = 0; i < 32; ++i) acc[i] = 0.f;
  for (int h = 0; h < H; h += 4) {
    const float w0 = Wm[(h + 0) * H + k];
    const float w1 = Wm[(h + 1) * H + k];
    const float w2 = Wm[(h + 2) * H + k];
    const float w3 = Wm[(h + 3) * H + k];
#pragma unroll
    for (int mi = 0; mi < 32; ++mi) {
      const float4 x = *reinterpret_cast<const float4*>(xb + (size_t)mi * H + h);
      acc[mi] += x.x * w0 + x.y * w1 + x.z * w2 + x.w * w3;
    }
  }
#pragma unroll
  for (int mi = 0; mi < 32; ++mi) keys[(size_t)(m0 + mi) * H + k] = acc[mi];
}

// Repack GRU weight [K,768] into gate-interleaved [K][j*4+g] (g=0:z,1:r,2:c).
__global__ __launch_bounds__(256) void k_pack(const float* __restrict__ W,
                                              float* __restrict__ Wp, int K) {
  const int idx = blockIdx.x * 256 + threadIdx.x;
  if (idx >= K * H3) return;
  const int k = idx / H3;
  const int c = idx % H3;
  const int g = c >> 8;
  const int j = c & 255;
  Wp[(size_t)k * 1024 + j * 4 + g] = W[idx];
}

// ---------------------------------------------------------------------------
// Phase workers (device functions; whole block participates, role is
// block-uniform so internal __syncthreads are legal).

// per-b: dense(t-1) -> 5 output frames; prenet(t) -> preT[j][b]
__device__ void dense_prenet(int t, int b, const float* __restrict__ outs,
                             const float* __restrict__ res1,
                             const float* __restrict__ Wo, const float* __restrict__ bo,
                             const float* __restrict__ Wp0, const float* __restrict__ bp0,
                             const float* __restrict__ Wp1, const float* __restrict__ bp1,
                             float* __restrict__ preT, float* __restrict__ dout,
                             float* lds) {
  const int tid = threadIdx.x;
  float* r1 = lds;          // 256
  float* f  = lds + 256;    // 96
  float* p0 = lds + 352;    // 256
  float* pp = lds + 608;    // 512
  if (t > 0) {
    if (tid < 256) r1[tid] = res1[tid * B + b];
    __syncthreads();
    const int q = tid >> 7, d = tid & 127;
    float acc = 0.f;
    if (d < D) {
      const int k0 = q * 64;
#pragma unroll 4
      for (int k = k0; k < k0 + 64; ++k) acc += r1[k] * Wo[k * D + d];
    }
    pp[tid] = acc;
    __syncthreads();
    if (tid < D) {
      const float dv = bo[tid] + pp[tid] + pp[128 + tid] + pp[256 + tid] + pp[384 + tid];
      const size_t base = (size_t)(t - 1) * RF * (B * D) + (size_t)b * D + tid;
      for (int i = 0; i < RF; ++i) dout[base + (size_t)i * (B * D)] = dv;
    }
  }
  if (t >= RSTEPS) return;
  if (tid < D) f[tid] = (t == 0) ? 0.f : outs[(size_t)(t * RF - 1) * (B * D) + b * D + tid];
  __syncthreads();
  {  // prenet L0: K=80 split 2-way, 256 j
    const int kh = tid >> 8, j = tid & 255;
    float acc = 0.f;
    const int k0 = kh * 40;
#pragma unroll 4
    for (int k = k0; k < k0 + 40; ++k) acc += f[k] * Wp0[k * H + j];
    pp[kh * 256 + j] = acc;
  }
  __syncthreads();
  if (tid < H) p0[tid] = fmaxf(bp0[tid] + pp[tid] + pp[256 + tid], 0.f);
  __syncthreads();
  {  // prenet L1: K=256 split 4-way, 128 j
    const int kq = tid >> 7, j = tid & 127;
    float acc = 0.f;
    const int k0 = kq * 64;
#pragma unroll 4
    for (int k = k0; k < k0 + 64; ++k) acc += p0[k] * Wp1[k * PP + j];
    pp[tid] = acc;
  }
  __syncthreads();
  if (tid < PP)
    preT[tid * B + b] =
        fmaxf(bp1[tid] + pp[tid] + pp[128 + tid] + pp[256 + tid] + pp[384 + tid], 0.f);
}

// h-part of a GRU: out[g][j][b] = sum_k Wp[k][j].g * h[k][b]   (K=256)
__device__ void gru_hpart(const float* __restrict__ Wp, const float* __restrict__ hbuf,
                          float* __restrict__ outp, int rel, float* lds) {
  const int tid = threadIdx.x, lane = tid & 63, wv = tid >> 6;
  const int j0 = (rel >> 1) * 4, bh = rel & 1, b = bh * 64 + lane;
  float a[12];
#pragma unroll
  for (int i = 0; i < 12; ++i) a[i] = 0.f;
  const int k0 = wv * 32;
#pragma unroll 2
  for (int k = k0; k < k0 + 32; ++k) {
    const float xv = hbuf[k * B + b];
    const float* wr = Wp + (size_t)k * 1024 + j0 * 4;
#pragma unroll
    for (int ji = 0; ji < 4; ++ji) {
      const float4 w = *reinterpret_cast<const float4*>(wr + ji * 4);
      a[ji * 3 + 0] += w.x * xv;
      a[ji * 3 + 1] += w.y * xv;
      a[ji * 3 + 2] += w.z * xv;
    }
  }
  float* pw = lds + wv * 768;
#pragma unroll
  for (int i = 0; i < 12; ++i) pw[i * 64 + lane] = a[i];
  __syncthreads();
  for (int idx = tid; idx < 768; idx += NTHR) {
    float s = 0.f;
#pragma unroll
    for (int w = 0; w < 8; ++w) s += lds[w * 768 + idx];
    const int i = idx >> 6, l2 = idx & 63;
    const int ji = i / 3, g = i - ji * 3;
    outp[((size_t)g * H + (j0 + ji)) * B + bh * 64 + l2] = s;
  }
}

// x-part + gate fusion: x = [x1 ; x2], combine with stored h-part, blend state.
__device__ void gru_xgate(const float* __restrict__ Wp, int Kx,
                          const float* __restrict__ x1, const float* __restrict__ x2,
                          const float* __restrict__ hpart, const float* __restrict__ b3,
                          float* __restrict__ hbuf, const float* __restrict__ resin,
                          float* __restrict__ resout, int rel, float* lds) {
  const int tid = threadIdx.x, lane = tid & 63, wv = tid >> 6;
  const int j0 = (rel >> 1) * 4, bh = rel & 1, b = bh * 64 + lane;
  const int KS = Kx >> 3;
  const int K1 = x2 ? 256 : Kx;
  float a[12];
#pragma unroll
  for (int i = 0; i < 12; ++i) a[i] = 0.f;
  const int k0 = wv * KS, k1 = k0 + KS;
  const int e1 = (k1 < K1) ? k1 : K1;
#pragma unroll 2
  for (int k = k0; k < e1; ++k) {
    const float xv = x1[k * B + b];
    const float* wr = Wp + (size_t)k * 1024 + j0 * 4;
#pragma unroll
    for (int ji = 0; ji < 4; ++ji) {
      const float4 w = *reinterpret_cast<const float4*>(wr + ji * 4);
      a[ji * 3 + 0] += w.x * xv;
      a[ji * 3 + 1] += w.y * xv;
      a[ji * 3 + 2] += w.z * xv;
    }
  }
  const int s2 = (k0 > K1) ? k0 : K1;
#pragma unroll 2
  for (int k = s2; k < k1; ++k) {
    const float xv = x2[(k - K1) * B + b];
    const float* wr = Wp + (size_t)k * 1024 + j0 * 4;
#pragma unroll
    for (int ji = 0; ji < 4; ++ji) {
      const float4 w = *reinterpret_cast<const float4*>(wr + ji * 4);
      a[ji * 3 + 0] += w.x * xv;
      a[ji * 3 + 1] += w.y * xv;
      a[ji * 3 + 2] += w.z * xv;
    }
  }
  float* pw = lds + wv * 768;
#pragma unroll
  for (int i = 0; i < 12; ++i) pw[i * 64 + lane] = a[i];
  __syncthreads();
  if (tid < 256) {
    const int ji = tid >> 6, l2 = tid & 63;
    const int j = j0 + ji, bb = bh * 64 + l2;
    float ax = 0.f, arr = 0.f, ac = 0.f;
#pragma unroll
    for (int w = 0; w < 8; ++w) {
      ax  += lds[w * 768 + (ji * 3 + 0) * 64 + l2];
      arr += lds[w * 768 + (ji * 3 + 1) * 64 + l2];
      ac  += lds[w * 768 + (ji * 3 + 2) * 64 + l2];
    }
    const float hz = hpart[((size_t)0 * H + j) * B + bb];
    const float hr = hpart[((size_t)1 * H + j) * B + bb];
    const float hc = hpart[((size_t)2 * H + j) * B + bb];
    const float z = sigm(ax + hz + b3[j]);
    const float r = sigm(arr + hr + b3[H + j]);
    const float c = tanh_(ac + r * hc + b3[2 * H + j]);
    const float hold = hbuf[j * B + bb];
    const float hn = (1.f - z) * hold + z * c;
    hbuf[j * B + bb] = hn;
    if (resout) resout[j * B + bb] = resin[j * B + bb] + hn;
  }
}

// qW: qk[b][col] = sum_k query[k][b] * Wq[k][col]
__device__ void qw_worker(const float* __restrict__ Wq, const float* __restrict__ query,
                          float* __restrict__ qk, int rel, float* lds) {
  const int tid = threadIdx.x, lane = tid & 63, wv = tid >> 6;
  const int c0 = (rel >> 1) * 4, bh = rel & 1, b = bh * 64 + lane;
  float a[4] = {0.f, 0.f, 0.f, 0.f};
  const int k0 = wv * 32;
#pragma unroll 4
  for (int k = k0; k < k0 + 32; ++k) {
    const float4 w = *reinterpret_cast<const float4*>(Wq + (size_t)k * H + c0);
    const float xv = query[k * B + b];
    a[0] += w.x * xv; a[1] += w.y * xv; a[2] += w.z * xv; a[3] += w.w * xv;
  }
  float* pw = lds + wv * 256;
#pragma unroll
  for (int i = 0; i < 4; ++i) pw[i * 64 + lane] = a[i];
  __syncthreads();
  if (tid < 256) {
    const int ci = tid >> 6, l2 = tid & 63;
    float s = 0.f;
#pragma unroll
    for (int w = 0; w < 8; ++w) s += lds[w * 256 + ci * 64 + l2];
    qk[(size_t)(bh * 64 + l2) * H + c0 + ci] = s;
  }
}

// e-pass + flash partial context for (b, t-tile of 128)
__device__ void attn_stream(int p, const float* __restrict__ qk,
                            const float* __restrict__ v_att, const float* __restrict__ keys,
                            const float* __restrict__ mem, float* __restrict__ pvals,
                            float* __restrict__ m_s, float* __restrict__ pctx, float* lds) {
  const int tid = threadIdx.x, lane = tid & 63, wv = tid >> 6;
  const int b = p >> 2, tile = p & 3, t0 = tile * 128;
  float* qkl = lds;          // 256
  float* vl  = lds + 256;    // 256
  float* el  = lds + 512;    // 128
  float* r8  = lds + 640;    // 8 (+pad)
  float* pcl = lds + 704;    // 2048
  if (tid < 256) { qkl[tid] = qk[(size_t)b * H + tid]; vl[tid] = v_att[tid]; }
  __syncthreads();
  const int lg = lane >> 4, l16 = lane & 15;
  float qg[16], vg[16];
#pragma unroll
  for (int i = 0; i < 16; ++i) { qg[i] = qkl[l16 + 16 * i]; vg[i] = vl[l16 + 16 * i]; }
  float wmax = -1e30f;
#pragma unroll
  for (int ss = 0; ss < 4; ++ss) {
    const int tl = wv * 16 + ss * 4 + lg;
    const float* kr = keys + ((size_t)(t0 + tl) * B + b) * H;
    float s = 0.f;
#pragma unroll
    for (int i = 0; i < 16; ++i) s += vg[i] * tanh_(kr[l16 + 16 * i] + qg[i]);
#pragma unroll
    for (int m = 1; m < 16; m <<= 1) s += __shfl_xor(s, m, 16);
    wmax = fmaxf(wmax, s);
    if (l16 == 0) el[tl] = s;
  }
  wmax = fmaxf(wmax, __shfl_xor(wmax, 16));
  wmax = fmaxf(wmax, __shfl_xor(wmax, 32));
  if (lane == 0) r8[wv] = wmax;
  __syncthreads();
  float m = r8[0];
#pragma unroll
  for (int w = 1; w < 8; ++w) m = fmaxf(m, r8[w]);
  if (tid < 128) {
    const float pt = __expf(el[tid] - m);
    el[tid] = pt;
    pvals[(size_t)b * TIN + t0 + tid] = pt;
  }
  __syncthreads();
  if (wv == 0) {
    float s = el[lane] + el[lane + 64];
#pragma unroll
    for (int mm = 1; mm < 64; mm <<= 1) s += __shfl_xor(s, mm);
    if (lane == 0) { m_s[((size_t)b * 4 + tile) * 2] = m; m_s[((size_t)b * 4 + tile) * 2 + 1] = s; }
  }
  float pc[4] = {0.f, 0.f, 0.f, 0.f};
  for (int ii = 0; ii < 16; ++ii) {
    const int tl = wv * 16 + ii;
    const float pv = el[tl];
    const float* mr = mem + ((size_t)(t0 + tl) * B + b) * H;
#pragma unroll
    for (int i = 0; i < 4; ++i) pc[i] += pv * mr[lane + i * 64];
  }
#pragma unroll
  for (int i = 0; i < 4; ++i) pcl[wv * 256 + i * 64 + lane] = pc[i];
  __syncthreads();
  if (tid < 256) {
    float s = 0.f;
#pragma unroll
    for (int w = 0; w < 8; ++w) s += pcl[w * 256 + tid];
    pctx[((size_t)b * 4 + tile) * H + tid] = s;
  }
}

// finalize: global max/sum across 4 tiles, ctx, alpha
__device__ void attn_final(int t, int b, const float* __restrict__ m_s,
                           const float* __restrict__ pctx, const float* __restrict__ pvals,
                           float* __restrict__ ctxT, float* __restrict__ alpha) {
  const int tid = threadIdx.x;
  float mm[4], ss[4];
#pragma unroll
  for (int i = 0; i < 4; ++i) {
    mm[i] = m_s[((size_t)b * 4 + i) * 2];
    ss[i] = m_s[((size_t)b * 4 + i) * 2 + 1];
  }
  const float M = fmaxf(fmaxf(mm[0], mm[1]), fmaxf(mm[2], mm[3]));
  float fct[4], S = 0.f;
#pragma unroll
  for (int i = 0; i < 4; ++i) { fct[i] = __expf(mm[i] - M); S += ss[i] * fct[i]; }
  const float inv = 1.f / S;
  if (tid < 256) {
    float s = 0.f;
#pragma unroll
    for (int i = 0; i < 4; ++i) s += pctx[((size_t)b * 4 + i) * H + tid] * fct[i];
    ctxT[tid * B + b] = s * inv;
  }
  const int tile = tid >> 7;
  alpha[((size_t)t * B + b) * TIN + tid] = pvals[(size_t)b * TIN + tid] * fct[tile] * inv;
}

// ---------------------------------------------------------------------------
__global__ __launch_bounds__(NTHR, 4) void k_step_fused(
    const float* __restrict__ outs, const float* __restrict__ mem,
    const float* __restrict__ keys,
    const float* __restrict__ Wp0, const float* __restrict__ bp0,
    const float* __restrict__ Wp1, const float* __restrict__ bp1,
    const float* __restrict__ wxp_att, const float* __restrict__ whp_att,
    const float* __restrict__ b_att, const float* __restrict__ Wq,
    const float* __restrict__ v_att,
    const float* __restrict__ wxp_d0, const float* __restrict__ whp_d0,
    const float* __restrict__ b_d0,
    const float* __restrict__ wxp_d1, const float* __restrict__ whp_d1,
    const float* __restrict__ b_d1,
    const float* __restrict__ Wo, const float* __restrict__ bo,
    float* preT, float* hpA, float* hpD0, float* hpD1,
    float* query, float* qk, float* pvals, float* m_s, float* pctx,
    float* ctxT, float* hd0, float* hd1, float* res0, float* res1,
    float* dout, float* alpha, unsigned* cnt) {
  __shared__ float lds[6144];
  const int p = blockIdx.x;
  unsigned n = 0;
  for (int t = 0; t < RSTEPS; ++t) {
    // P1: per-b dense+prenet | att-h | d0-h | d1-h  (all states are t-1)
    if (p < 128)      dense_prenet(t, p, outs, res1, Wo, bo, Wp0, bp0, Wp1, bp1, preT, dout, lds);
    else if (p < 256) gru_hpart(whp_att, query, hpA, p - 128, lds);
    else if (p < 384) gru_hpart(whp_d0, hd0, hpD0, p - 256, lds);
    else              gru_hpart(whp_d1, hd1, hpD1, p - 384, lds);
    gbar(cnt, n);
    // P2: attention GRU x-part + gates -> query (in place of h_att)
    if (p < 128) gru_xgate(wxp_att, PP, preT, nullptr, hpA, b_att, query, nullptr, nullptr, p, lds);
    gbar(cnt, n);
    // P3: qW
    if (p < 128) qw_worker(Wq, query, qk, p, lds);
    gbar(cnt, n);
    // P4: e + flash partial ctx (all 512 blocks stream keys+memory)
    attn_stream(p, qk, v_att, keys, mem, pvals, m_s, pctx, lds);
    gbar(cnt, n);
    // P5: finalize softmax, ctx, alpha
    if (p < 128) attn_final(t, p, m_s, pctx, pvals, ctxT, dout + (size_t)1000 * B * D);
    gbar(cnt, n);
    // P6: decoder GRU 0
    if (p < 128) gru_xgate(wxp_d0, 2 * H, query, ctxT, hpD0, b_d0, hd0, query, res0, p, lds);
    gbar(cnt, n);
    // P7: decoder GRU 1
    if (p < 128) gru_xgate(wxp_d1, H, res0, nullptr, hpD1, b_d1, hd1, res0, res1, p, lds);
    gbar(cnt, n);
  }
  // final dense for step 199
  if (p < 128) dense_prenet(RSTEPS, p, outs, res1, Wo, bo, Wp0, bp0, Wp1, bp1, preT, dout, lds);
}

// ---------------------------------------------------------------------------
extern "C" void kernel_launch(void* const* d_in, const int* in_sizes, int n_in,
                              void* d_out, int out_size, void* d_ws,
                              size_t ws_size, hipStream_t stream) {
  const float* outs   = (const float*)d_in[0];
  const float* memory = (const float*)d_in[1];
  const float* Wp0    = (const float*)d_in[2];
  const float* bp0    = (const float*)d_in[3];
  const float* Wp1    = (const float*)d_in[4];
  const float* bp1    = (const float*)d_in[5];
  const float* Wx_att = (const float*)d_in[6];
  const float* Wh_att = (const float*)d_in[7];
  const float* b_att  = (const float*)d_in[8];
  const float* Wq     = (const float*)d_in[9];
  const float* Wm     = (const float*)d_in[10];
  const float* v_att  = (const float*)d_in[11];
  const float* Wx_d0  = (const float*)d_in[12];
  const float* Wh_d0  = (const float*)d_in[13];
  const float* b_d0   = (const float*)d_in[14];
  const float* Wx_d1  = (const float*)d_in[15];
  const float* Wh_d1  = (const float*)d_in[16];
  const float* b_d1   = (const float*)d_in[17];
  const float* Wo     = (const float*)d_in[18];
  const float* bo     = (const float*)d_in[19];
  float* dout = (float*)d_out;
  float* wsf  = (float*)d_ws;

  size_t off = 0;
  float* keys    = wsf + off; off += (size_t)TIN * B * H;   // 16.78M
  float* wxp_att = wsf + off; off += (size_t)128 * 1024;
  float* whp_att = wsf + off; off += (size_t)256 * 1024;
  float* wxp_d0  = wsf + off; off += (size_t)512 * 1024;
  float* whp_d0  = wsf + off; off += (size_t)256 * 1024;
  float* wxp_d1  = wsf + off; off += (size_t)256 * 1024;
  float* whp_d1  = wsf + off; off += (size_t)256 * 1024;
  float* preT  = wsf + off; off += (size_t)PP * B;
  float* hpA   = wsf + off; off += (size_t)3 * H * B;
  float* hpD0  = wsf + off; off += (size_t)3 * H * B;
  float* hpD1  = wsf + off; off += (size_t)3 * H * B;
  float* query = wsf + off; off += (size_t)H * B;
  float* qk    = wsf + off; off += (size_t)B * H;
  float* pvals = wsf + off; off += (size_t)B * TIN;
  float* m_s   = wsf + off; off += (size_t)B * 4 * 2;
  float* pctx  = wsf + off; off += (size_t)B * 4 * H;
  float* ctxT  = wsf + off; off += (size_t)H * B;
  float* hd0   = wsf + off; off += (size_t)H * B;
  float* hd1   = wsf + off; off += (size_t)H * B;
  float* res0  = wsf + off; off += (size_t)H * B;
  float* res1  = wsf + off; off += (size_t)H * B;
  unsigned* cnt = (unsigned*)(wsf + off); off += 64;

  // zero initial states + barrier counter (every call: deterministic)
  hipMemsetAsync(query, 0, (size_t)H * B * sizeof(float), stream);
  hipMemsetAsync(hd0, 0, (size_t)H * B * sizeof(float), stream);
  hipMemsetAsync(hd1, 0, (size_t)H * B * sizeof(float), stream);
  hipMemsetAsync(cnt, 0, sizeof(unsigned), stream);

  // one-time precompute
  k_keys<<<(TIN * B) / 32, 256, 0, stream>>>(memory, Wm, keys);
  k_pack<<<(128 * H3 + 255) / 256, 256, 0, stream>>>(Wx_att, wxp_att, 128);
  k_pack<<<(256 * H3 + 255) / 256, 256, 0, stream>>>(Wh_att, whp_att, 256);
  k_pack<<<(512 * H3 + 255) / 256, 256, 0, stream>>>(Wx_d0, wxp_d0, 512);
  k_pack<<<(256 * H3 + 255) / 256, 256, 0, stream>>>(Wh_d0, whp_d0, 256);
  k_pack<<<(256 * H3 + 255) / 256, 256, 0, stream>>>(Wx_d1, wxp_d1, 256);
  k_pack<<<(256 * H3 + 255) / 256, 256, 0, stream>>>(Wh_d1, whp_d1, 256);

  k_step_fused<<<GRID, NTHR, 0, stream>>>(
      outs, memory, keys, Wp0, bp0, Wp1, bp1, wxp_att, whp_att, b_att, Wq, v_att,
      wxp_d0, whp_d0, b_d0, wxp_d1, whp_d1, b_d1, Wo, bo,
      preT, hpA, hpD0, hpD1, query, qk, pvals, m_s, pctx, ctxT, hd0, hd1,
      res0, res1, dout, dout + (size_t)1000 * B * D, cnt);
}

// Round 4
// 90131.757 us; speedup vs baseline: 1.8171x; 1.8171x over previous
//
#include <hip/hip_runtime.h>

namespace {
constexpr int B = 128;      // batch
constexpr int D = 80;       // mel dim
constexpr int H = 256;      // hidden
constexpr int PP = 128;     // prenet out
constexpr int TIN = 512;    // encoder steps
constexpr int RSTEPS = 200; // reduced steps
constexpr int RF = 5;       // reduction factor
}

__device__ __forceinline__ float sigm(float x) { return 1.f / (1.f + __expf(-x)); }
__device__ __forceinline__ float tanh_(float x) { return 1.f - 2.f / (__expf(2.f * x) + 1.f); }

// ---------------------------------------------------------------------------
// keys[t,b,k] = sum_h memory[t,b,h] * Wm[h,k]   (one-time per call; proven)
__global__ __launch_bounds__(256) void k_keys(const float* __restrict__ mem,
                                              const float* __restrict__ Wm,
                                              float* __restrict__ keys) {
  const int k = threadIdx.x;
  const int m0 = blockIdx.x * 32;
  const float* xb = mem + (size_t)m0 * H;
  float acc[32];
#pragma unroll
  for (int i = 0; i < 32; ++i) acc[i] = 0.f;
  for (int h = 0; h < H; h += 4) {
    const float w0 = Wm[(h + 0) * H + k];
    const float w1 = Wm[(h + 1) * H + k];
    const float w2 = Wm[(h + 2) * H + k];
    const float w3 = Wm[(h + 3) * H + k];
#pragma unroll
    for (int mi = 0; mi < 32; ++mi) {
      const float4 x = *reinterpret_cast<const float4*>(xb + (size_t)mi * H + h);
      acc[mi] += x.x * w0 + x.y * w1 + x.z * w2 + x.w * w3;
    }
  }
#pragma unroll
  for (int mi = 0; mi < 32; ++mi) keys[(size_t)(m0 + mi) * H + k] = acc[mi];
}

// ---------------------------------------------------------------------------
// Persistent per-batch-row block: the entire 200-step recurrence for b =
// blockIdx.x. All state in LDS; zero inter-block communication.
__global__ __launch_bounds__(1024, 4) void k_step(
    const float* __restrict__ outs, const float* __restrict__ mem,
    const float* __restrict__ keys,
    const float* __restrict__ Wp0, const float* __restrict__ bp0,
    const float* __restrict__ Wp1, const float* __restrict__ bp1,
    const float* __restrict__ Wx_att, const float* __restrict__ Wh_att,
    const float* __restrict__ b_att, const float* __restrict__ Wq,
    const float* __restrict__ v_att,
    const float* __restrict__ Wx_d0, const float* __restrict__ Wh_d0,
    const float* __restrict__ b_d0,
    const float* __restrict__ Wx_d1, const float* __restrict__ Wh_d1,
    const float* __restrict__ b_d1,
    const float* __restrict__ Wo, const float* __restrict__ bo,
    float* __restrict__ dout, float* __restrict__ alpha) {
  const int b = blockIdx.x;
  const int tid = threadIdx.x;
  const int lane = tid & 63, wv = tid >> 6;

  __shared__ float f_l[96];
  __shared__ float p0_l[256];
  __shared__ float pre_l[128];
  __shared__ float hA[256], hD0[256], hD1[256];
  __shared__ float qk_l[256], ctx_l[256], res0_l[256], res1_l[256];
  __shared__ float yx[768], yh[768];
  __shared__ float ep[512];
  __shared__ float scr[1024];
  __shared__ float r16[16];
  __shared__ float bc[2];

  if (tid < 256) { hA[tid] = 0.f; hD0[tid] = 0.f; hD1[tid] = 0.f; }
  __syncthreads();

  for (int t = 0; t < RSTEPS; ++t) {
    // ---- teacher-forcing frame ----
    if (tid < 96) f_l[tid] = 0.f;
    __syncthreads();
    if (t > 0 && tid < D)
      f_l[tid] = outs[(size_t)(t * RF - 1) * (B * D) + b * D + tid];
    __syncthreads();

    // ---- prenet L0: 256 cols, K=80 (4-way split) ----
    {
      const int c = tid & 255, ks = tid >> 8;
      float a = 0.f;
      const int k0 = ks * 20;
#pragma unroll
      for (int k = k0; k < k0 + 20; ++k) a += f_l[k] * Wp0[k * 256 + c];
      scr[ks * 256 + c] = a;
    }
    __syncthreads();
    if (tid < 256)
      p0_l[tid] = fmaxf(bp0[tid] + scr[tid] + scr[256 + tid] + scr[512 + tid] + scr[768 + tid], 0.f);
    __syncthreads();

    // ---- prenet L1: 128 cols, K=256 (8-way split) ----
    {
      const int c = tid & 127, ks = tid >> 7;
      float a = 0.f;
      const int k0 = ks * 32;
#pragma unroll 4
      for (int k = k0; k < k0 + 32; ++k) a += p0_l[k] * Wp1[k * 128 + c];
      scr[ks * 128 + c] = a;
    }
    __syncthreads();
    if (tid < 128) {
      float s = bp1[tid];
#pragma unroll
      for (int ks = 0; ks < 8; ++ks) s += scr[ks * 128 + tid];
      pre_l[tid] = fmaxf(s, 0.f);
    }
    __syncthreads();

    // ---- attention GRU GEMV: 768 cols, x(K=128) + h(K=256) ----
    if (tid < 768) {
      float ax = 0.f, ah = 0.f;
#pragma unroll 4
      for (int k = 0; k < PP; ++k) ax += pre_l[k] * Wx_att[k * 768 + tid];
#pragma unroll 4
      for (int k = 0; k < H; ++k) ah += hA[k] * Wh_att[k * 768 + tid];
      yx[tid] = ax; yh[tid] = ah;
    }
    __syncthreads();
    if (tid < 256) {
      const float z = sigm(yx[tid] + yh[tid] + b_att[tid]);
      const float r = sigm(yx[256 + tid] + yh[256 + tid] + b_att[256 + tid]);
      const float cc = tanh_(yx[512 + tid] + r * yh[512 + tid] + b_att[512 + tid]);
      const float hold = hA[tid];
      hA[tid] = (1.f - z) * hold + z * cc;   // = query
    }
    __syncthreads();

    // ---- qW: 256 cols, K=256 (4-way split) ----
    {
      const int c = tid & 255, ks = tid >> 8;
      float a = 0.f;
      const int k0 = ks * 64;
#pragma unroll 4
      for (int k = k0; k < k0 + 64; ++k) a += hA[k] * Wq[k * 256 + c];
      scr[ks * 256 + c] = a;
    }
    __syncthreads();
    if (tid < 256)
      qk_l[tid] = scr[tid] + scr[256 + tid] + scr[512 + tid] + scr[768 + tid];
    __syncthreads();

    // ---- e-pass: 16-lane groups, 4 t per wave-pass, 8 passes ----
    {
      const int l16 = lane & 15, lg = lane >> 4;
      float qg[16], vg[16];
#pragma unroll
      for (int i = 0; i < 16; ++i) {
        qg[i] = qk_l[l16 + 16 * i];
        vg[i] = v_att[l16 + 16 * i];
      }
#pragma unroll 2
      for (int ss = 0; ss < 8; ++ss) {
        const int tl = wv * 32 + ss * 4 + lg;
        const float* kr = keys + ((size_t)tl * B + b) * H;
        float s = 0.f;
#pragma unroll
        for (int i = 0; i < 16; ++i) s += vg[i] * tanh_(kr[l16 + 16 * i] + qg[i]);
#pragma unroll
        for (int m = 1; m < 16; m <<= 1) s += __shfl_xor(s, m, 16);
        if (l16 == 0) ep[tl] = s;
      }
    }
    __syncthreads();

    // ---- softmax over 512 (waves 0..7 own ep) ----
    float ev = -1e30f, pv = 0.f;
    if (tid < TIN) {
      ev = ep[tid];
      float mx = ev;
#pragma unroll
      for (int m = 1; m < 64; m <<= 1) mx = fmaxf(mx, __shfl_xor(mx, m));
      if (lane == 0) r16[wv] = mx;
    }
    __syncthreads();
    if (tid == 0) {
      float g = r16[0];
#pragma unroll
      for (int w = 1; w < 8; ++w) g = fmaxf(g, r16[w]);
      bc[0] = g;
    }
    __syncthreads();
    const float M = bc[0];
    if (tid < TIN) {
      pv = __expf(ev - M);
      ep[tid] = pv;
      float s = pv;
#pragma unroll
      for (int m = 1; m < 64; m <<= 1) s += __shfl_xor(s, m);
      if (lane == 0) r16[wv] = s;
    }
    __syncthreads();
    if (tid == 0) {
      float s = 0.f;
#pragma unroll
      for (int w = 0; w < 8; ++w) s += r16[w];
      bc[1] = 1.f / s;
    }
    __syncthreads();
    const float inv = bc[1];
    if (tid < TIN) alpha[((size_t)t * B + b) * TIN + tid] = pv * inv;

    // ---- context: 256 k, t split 4-way x 128 ----
    {
      const int k = tid & 255, ch = tid >> 8;
      float a = 0.f;
      const int t0 = ch * 128;
#pragma unroll 4
      for (int i = 0; i < 128; ++i) {
        const int tt = t0 + i;
        a += ep[tt] * mem[((size_t)tt * B + b) * H + k];
      }
      scr[ch * 256 + k] = a;
    }
    __syncthreads();
    if (tid < 256)
      ctx_l[tid] = inv * (scr[tid] + scr[256 + tid] + scr[512 + tid] + scr[768 + tid]);
    __syncthreads();

    // ---- decoder GRU 0: x = [query; ctx] (K=512) + h (K=256) ----
    if (tid < 768) {
      float ax = 0.f, ah = 0.f;
#pragma unroll 4
      for (int k = 0; k < H; ++k) ax += hA[k] * Wx_d0[k * 768 + tid];
#pragma unroll 4
      for (int k = 0; k < H; ++k) ax += ctx_l[k] * Wx_d0[(H + k) * 768 + tid];
#pragma unroll 4
      for (int k = 0; k < H; ++k) ah += hD0[k] * Wh_d0[k * 768 + tid];
      yx[tid] = ax; yh[tid] = ah;
    }
    __syncthreads();
    if (tid < 256) {
      const float z = sigm(yx[tid] + yh[tid] + b_d0[tid]);
      const float r = sigm(yx[256 + tid] + yh[256 + tid] + b_d0[256 + tid]);
      const float cc = tanh_(yx[512 + tid] + r * yh[512 + tid] + b_d0[512 + tid]);
      const float hold = hD0[tid];
      const float hn = (1.f - z) * hold + z * cc;
      hD0[tid] = hn;
      res0_l[tid] = hA[tid] + hn;
    }
    __syncthreads();

    // ---- decoder GRU 1: x = res0 (K=256) + h (K=256) ----
    if (tid < 768) {
      float ax = 0.f, ah = 0.f;
#pragma unroll 4
      for (int k = 0; k < H; ++k) ax += res0_l[k] * Wx_d1[k * 768 + tid];
#pragma unroll 4
      for (int k = 0; k < H; ++k) ah += hD1[k] * Wh_d1[k * 768 + tid];
      yx[tid] = ax; yh[tid] = ah;
    }
    __syncthreads();
    if (tid < 256) {
      const float z = sigm(yx[tid] + yh[tid] + b_d1[tid]);
      const float r = sigm(yx[256 + tid] + yh[256 + tid] + b_d1[256 + tid]);
      const float cc = tanh_(yx[512 + tid] + r * yh[512 + tid] + b_d1[512 + tid]);
      const float hold = hD1[tid];
      const float hn = (1.f - z) * hold + z * cc;
      hD1[tid] = hn;
      res1_l[tid] = res0_l[tid] + hn;
    }
    __syncthreads();

    // ---- dense: 80 cols, K=256 (8-way split) -> 5 output frames ----
    {
      const int c = tid & 127, ks = tid >> 7;
      float a = 0.f;
      if (c < D) {
        const int k0 = ks * 32;
#pragma unroll 4
        for (int k = k0; k < k0 + 32; ++k) a += res1_l[k] * Wo[k * D + c];
      }
      scr[ks * 128 + c] = a;
    }
    __syncthreads();
    if (tid < D) {
      float dv = bo[tid];
#pragma unroll
      for (int ks = 0; ks < 8; ++ks) dv += scr[ks * 128 + tid];
      const size_t base = (size_t)t * RF * (B * D) + (size_t)b * D + tid;
#pragma unroll
      for (int i = 0; i < RF; ++i) dout[base + (size_t)i * (B * D)] = dv;
    }
    __syncthreads();  // scr/f_l reused next iteration
  }
}

// ---------------------------------------------------------------------------
extern "C" void kernel_launch(void* const* d_in, const int* in_sizes, int n_in,
                              void* d_out, int out_size, void* d_ws,
                              size_t ws_size, hipStream_t stream) {
  const float* outs   = (const float*)d_in[0];
  const float* memory = (const float*)d_in[1];
  const float* Wp0    = (const float*)d_in[2];
  const float* bp0    = (const float*)d_in[3];
  const float* Wp1    = (const float*)d_in[4];
  const float* bp1    = (const float*)d_in[5];
  const float* Wx_att = (const float*)d_in[6];
  const float* Wh_att = (const float*)d_in[7];
  const float* b_att  = (const float*)d_in[8];
  const float* Wq     = (const float*)d_in[9];
  const float* Wm     = (const float*)d_in[10];
  const float* v_att  = (const float*)d_in[11];
  const float* Wx_d0  = (const float*)d_in[12];
  const float* Wh_d0  = (const float*)d_in[13];
  const float* b_d0   = (const float*)d_in[14];
  const float* Wx_d1  = (const float*)d_in[15];
  const float* Wh_d1  = (const float*)d_in[16];
  const float* b_d1   = (const float*)d_in[17];
  const float* Wo     = (const float*)d_in[18];
  const float* bo     = (const float*)d_in[19];
  float* dout = (float*)d_out;
  float* keys = (float*)d_ws;  // TIN*B*H floats = 67 MB

  k_keys<<<(TIN * B) / 32, 256, 0, stream>>>(memory, Wm, keys);

  float* alpha = dout + (size_t)1000 * B * D;
  k_step<<<B, 1024, 0, stream>>>(outs, memory, keys, Wp0, bp0, Wp1, bp1,
                                 Wx_att, Wh_att, b_att, Wq, v_att,
                                 Wx_d0, Wh_d0, b_d0, Wx_d1, Wh_d1, b_d1,
                                 Wo, bo, dout, alpha);
}

// Round 5
// 44884.048 us; speedup vs baseline: 3.6488x; 2.0081x over previous
//
#include <hip/hip_runtime.h>

namespace {
constexpr int B = 128;      // batch
constexpr int D = 80;       // mel dim
constexpr int H = 256;      // hidden
constexpr int PP = 128;     // prenet out
constexpr int TIN = 512;    // encoder steps
constexpr int RSTEPS = 200; // reduced steps
constexpr int RF = 5;       // reduction factor
}

__device__ __forceinline__ float sigm(float x) { return 1.f / (1.f + __expf(-x)); }
__device__ __forceinline__ float tanh_(float x) { return 1.f - 2.f / (__expf(2.f * x) + 1.f); }

// ---------------------------------------------------------------------------
// keys[t,b,k] = sum_h memory[t,b,h] * Wm[h,k]   (one-time per call; proven)
__global__ __launch_bounds__(256) void k_keys(const float* __restrict__ mem,
                                              const float* __restrict__ Wm,
                                              float* __restrict__ keys) {
  const int k = threadIdx.x;
  const int m0 = blockIdx.x * 32;
  const float* xb = mem + (size_t)m0 * H;
  float acc[32];
#pragma unroll
  for (int i = 0; i < 32; ++i) acc[i] = 0.f;
  for (int h = 0; h < H; h += 4) {
    const float w0 = Wm[(h + 0) * H + k];
    const float w1 = Wm[(h + 1) * H + k];
    const float w2 = Wm[(h + 2) * H + k];
    const float w3 = Wm[(h + 3) * H + k];
#pragma unroll
    for (int mi = 0; mi < 32; ++mi) {
      const float4 x = *reinterpret_cast<const float4*>(xb + (size_t)mi * H + h);
      acc[mi] += x.x * w0 + x.y * w1 + x.z * w2 + x.w * w3;
    }
  }
#pragma unroll
  for (int mi = 0; mi < 32; ++mi) keys[(size_t)(m0 + mi) * H + k] = acc[mi];
}

// ---------------------------------------------------------------------------
// Hoisted prenet: frames are teacher-forced from INPUT outs, so all 200 steps
// are precomputable. pre[(t*B+b)*PP + j]. grid = 200*128, 256 threads.
__global__ __launch_bounds__(256) void k_prenet(
    const float* __restrict__ outs, const float* __restrict__ Wp0,
    const float* __restrict__ bp0, const float* __restrict__ Wp1,
    const float* __restrict__ bp1, float* __restrict__ pre) {
  const int t = blockIdx.x >> 7, b = blockIdx.x & 127, tid = threadIdx.x;
  __shared__ float f[80];
  __shared__ float p0[256];
  __shared__ float s2[256];
  if (tid < 80)
    f[tid] = (t == 0) ? 0.f
                      : __builtin_nontemporal_load(
                            &outs[((size_t)(t * RF - 1) * B + b) * D + tid]);
  __syncthreads();
  {
    float a = bp0[tid];
#pragma unroll 8
    for (int k = 0; k < 80; ++k) a += f[k] * Wp0[k * 256 + tid];
    p0[tid] = fmaxf(a, 0.f);
  }
  __syncthreads();
  {
    const int c = tid & 127, kh = tid >> 7;
    float a = 0.f;
#pragma unroll 8
    for (int k = kh * 128; k < kh * 128 + 128; ++k) a += p0[k] * Wp1[k * 128 + c];
    s2[kh * 128 + c] = a;
  }
  __syncthreads();
  if (tid < 128)
    pre[((size_t)t * B + b) * PP + tid] = fmaxf(bp1[tid] + s2[tid] + s2[128 + tid], 0.f);
}

// ---------------------------------------------------------------------------
// Persistent per-batch-row block: entire 200-step recurrence for b=blockIdx.x.
// All state in LDS; zero inter-block communication; NT stores for outputs.
__global__ __launch_bounds__(1024, 4) void k_step(
    const float* __restrict__ mem, const float* __restrict__ keys,
    const float* __restrict__ pre,
    const float* __restrict__ Wx_att, const float* __restrict__ Wh_att,
    const float* __restrict__ b_att, const float* __restrict__ Wq,
    const float* __restrict__ v_att,
    const float* __restrict__ Wx_d0, const float* __restrict__ Wh_d0,
    const float* __restrict__ b_d0,
    const float* __restrict__ Wx_d1, const float* __restrict__ Wh_d1,
    const float* __restrict__ b_d1,
    const float* __restrict__ Wo, const float* __restrict__ bo,
    float* __restrict__ dout, float* __restrict__ alpha) {
  const int b = blockIdx.x;
  const int tid = threadIdx.x;
  const int lane = tid & 63, wv = tid >> 6;

  __shared__ float hA[256], hD0[256], hD1[256];
  __shared__ float qk_l[256], ctx_l[256], res0_l[256], res1_l[256];
  __shared__ float pre_l[128];
  __shared__ float v_l[256];
  __shared__ float scr[4096];
  __shared__ float ep[512];
  __shared__ float r16[16];
  __shared__ float bc[2];

  if (tid < 256) { hA[tid] = 0.f; hD0[tid] = 0.f; hD1[tid] = 0.f; v_l[tid] = v_att[tid]; }
  __syncthreads();

  for (int t = 0; t < RSTEPS; ++t) {
    if (tid < PP) pre_l[tid] = pre[((size_t)t * B + b) * PP + tid];
    __syncthreads();

    // ---- attention GRU: thread (j, ks); partials z / r / c_x / c_h ----
    {
      const int j = tid & 255, ks = tid >> 8;
      float pz = 0, pr = 0, px = 0, ph = 0;
#pragma unroll 8
      for (int k = ks * 32; k < ks * 32 + 32; ++k) {
        const float xv = pre_l[k];
        const float* row = Wx_att + (size_t)k * 768;
        pz += row[j] * xv; pr += row[256 + j] * xv; px += row[512 + j] * xv;
      }
#pragma unroll 8
      for (int k = ks * 64; k < ks * 64 + 64; ++k) {
        const float hv = hA[k];
        const float* row = Wh_att + (size_t)k * 768;
        pz += row[j] * hv; pr += row[256 + j] * hv; ph += row[512 + j] * hv;
      }
      scr[ks * 1024 + j] = pz;       scr[ks * 1024 + 256 + j] = pr;
      scr[ks * 1024 + 512 + j] = px; scr[ks * 1024 + 768 + j] = ph;
    }
    __syncthreads();
    if (tid < 256) {
      float az = 0, ar = 0, acx = 0, ach = 0;
#pragma unroll
      for (int ks = 0; ks < 4; ++ks) {
        az += scr[ks * 1024 + tid];        ar += scr[ks * 1024 + 256 + tid];
        acx += scr[ks * 1024 + 512 + tid]; ach += scr[ks * 1024 + 768 + tid];
      }
      const float z = sigm(az + b_att[tid]);
      const float r = sigm(ar + b_att[256 + tid]);
      const float c = tanh_(acx + r * ach + b_att[512 + tid]);
      hA[tid] = (1.f - z) * hA[tid] + z * c;   // = query
    }
    __syncthreads();

    // ---- qW: thread (c, ks) ----
    {
      const int c = tid & 255, ks = tid >> 8;
      float a = 0.f;
#pragma unroll 8
      for (int k = ks * 64; k < ks * 64 + 64; ++k) a += hA[k] * Wq[k * 256 + c];
      scr[ks * 256 + c] = a;
    }
    __syncthreads();
    if (tid < 256)
      qk_l[tid] = scr[tid] + scr[256 + tid] + scr[512 + tid] + scr[768 + tid];
    __syncthreads();

    // ---- e-pass: 64 groups of 16 lanes; 2 t-rows in flight per pass ----
    {
      const int l16 = tid & 15, g = tid >> 4;
      float qg[16], vg[16];
#pragma unroll
      for (int i = 0; i < 16; ++i) { qg[i] = qk_l[l16 + 16 * i]; vg[i] = v_l[l16 + 16 * i]; }
#pragma unroll
      for (int p2 = 0; p2 < 4; ++p2) {
        const int t1 = g + p2 * 128, t2 = t1 + 64;
        const float* k1 = keys + ((size_t)t1 * B + b) * H;
        const float* k2 = keys + ((size_t)t2 * B + b) * H;
        float s1 = 0.f, s2 = 0.f;
#pragma unroll
        for (int i = 0; i < 16; ++i) {
          const float a1 = k1[l16 + 16 * i], a2 = k2[l16 + 16 * i];
          s1 += vg[i] * tanh_(a1 + qg[i]);
          s2 += vg[i] * tanh_(a2 + qg[i]);
        }
#pragma unroll
        for (int m = 1; m < 16; m <<= 1) { s1 += __shfl_xor(s1, m, 16); s2 += __shfl_xor(s2, m, 16); }
        if (l16 == 0) { ep[t1] = s1; ep[t2] = s2; }
      }
    }
    __syncthreads();

    // ---- softmax over 512 ----
    float ev = -1e30f, pv = 0.f;
    if (tid < TIN) {
      ev = ep[tid];
      float mx = ev;
#pragma unroll
      for (int m = 1; m < 64; m <<= 1) mx = fmaxf(mx, __shfl_xor(mx, m));
      if (lane == 0) r16[wv] = mx;
    }
    __syncthreads();
    if (tid == 0) {
      float g = r16[0];
#pragma unroll
      for (int w = 1; w < 8; ++w) g = fmaxf(g, r16[w]);
      bc[0] = g;
    }
    __syncthreads();
    const float M = bc[0];
    if (tid < TIN) {
      pv = __expf(ev - M);
      ep[tid] = pv;
      float s = pv;
#pragma unroll
      for (int m = 1; m < 64; m <<= 1) s += __shfl_xor(s, m);
      if (lane == 0) r16[wv] = s;
    }
    __syncthreads();
    if (tid == 0) {
      float s = 0.f;
#pragma unroll
      for (int w = 0; w < 8; ++w) s += r16[w];
      bc[1] = 1.f / s;
    }
    __syncthreads();
    const float inv = bc[1];
    if (tid < TIN)
      __builtin_nontemporal_store(pv * inv, &alpha[((size_t)t * B + b) * TIN + tid]);

    // ---- context: thread (k, 4 t-slices of 128) ----
    {
      const int kk = tid & 255, cs = tid >> 8;
      float a = 0.f;
      const int t0 = cs * 128;
#pragma unroll 8
      for (int i = 0; i < 128; ++i) {
        const int tt = t0 + i;
        a += ep[tt] * mem[((size_t)tt * B + b) * H + kk];
      }
      scr[cs * 256 + kk] = a;
    }
    __syncthreads();
    if (tid < 256)
      ctx_l[tid] = inv * (scr[tid] + scr[256 + tid] + scr[512 + tid] + scr[768 + tid]);
    __syncthreads();

    // ---- decoder GRU 0: x = [query(=hA); ctx] (K=512) + h (K=256) ----
    {
      const int j = tid & 255, ks = tid >> 8;
      float pz = 0, pr = 0, px = 0, ph = 0;
      const float* xs = (ks < 2) ? hA : ctx_l;
      const int kb = (ks & 1) * 128;
#pragma unroll 8
      for (int i = 0; i < 128; ++i) {
        const float xv = xs[kb + i];
        const float* row = Wx_d0 + (size_t)(ks * 128 + i) * 768;
        pz += row[j] * xv; pr += row[256 + j] * xv; px += row[512 + j] * xv;
      }
#pragma unroll 8
      for (int k = ks * 64; k < ks * 64 + 64; ++k) {
        const float hv = hD0[k];
        const float* row = Wh_d0 + (size_t)k * 768;
        pz += row[j] * hv; pr += row[256 + j] * hv; ph += row[512 + j] * hv;
      }
      scr[ks * 1024 + j] = pz;       scr[ks * 1024 + 256 + j] = pr;
      scr[ks * 1024 + 512 + j] = px; scr[ks * 1024 + 768 + j] = ph;
    }
    __syncthreads();
    if (tid < 256) {
      float az = 0, ar = 0, acx = 0, ach = 0;
#pragma unroll
      for (int ks = 0; ks < 4; ++ks) {
        az += scr[ks * 1024 + tid];        ar += scr[ks * 1024 + 256 + tid];
        acx += scr[ks * 1024 + 512 + tid]; ach += scr[ks * 1024 + 768 + tid];
      }
      const float z = sigm(az + b_d0[tid]);
      const float r = sigm(ar + b_d0[256 + tid]);
      const float c = tanh_(acx + r * ach + b_d0[512 + tid]);
      const float hn = (1.f - z) * hD0[tid] + z * c;
      hD0[tid] = hn;
      res0_l[tid] = hA[tid] + hn;
    }
    __syncthreads();

    // ---- decoder GRU 1: x = res0 (K=256) + h (K=256) ----
    {
      const int j = tid & 255, ks = tid >> 8;
      float pz = 0, pr = 0, px = 0, ph = 0;
#pragma unroll 8
      for (int k = ks * 64; k < ks * 64 + 64; ++k) {
        const float xv = res0_l[k];
        const float* row = Wx_d1 + (size_t)k * 768;
        pz += row[j] * xv; pr += row[256 + j] * xv; px += row[512 + j] * xv;
      }
#pragma unroll 8
      for (int k = ks * 64; k < ks * 64 + 64; ++k) {
        const float hv = hD1[k];
        const float* row = Wh_d1 + (size_t)k * 768;
        pz += row[j] * hv; pr += row[256 + j] * hv; ph += row[512 + j] * hv;
      }
      scr[ks * 1024 + j] = pz;       scr[ks * 1024 + 256 + j] = pr;
      scr[ks * 1024 + 512 + j] = px; scr[ks * 1024 + 768 + j] = ph;
    }
    __syncthreads();
    if (tid < 256) {
      float az = 0, ar = 0, acx = 0, ach = 0;
#pragma unroll
      for (int ks = 0; ks < 4; ++ks) {
        az += scr[ks * 1024 + tid];        ar += scr[ks * 1024 + 256 + tid];
        acx += scr[ks * 1024 + 512 + tid]; ach += scr[ks * 1024 + 768 + tid];
      }
      const float z = sigm(az + b_d1[tid]);
      const float r = sigm(ar + b_d1[256 + tid]);
      const float c = tanh_(acx + r * ach + b_d1[512 + tid]);
      const float hn = (1.f - z) * hD1[tid] + z * c;
      hD1[tid] = hn;
      res1_l[tid] = res0_l[tid] + hn;
    }
    __syncthreads();

    // ---- dense: 80 cols, 8 K-slices of 32 -> 5 output frames (NT) ----
    {
      const int c = tid & 127, ks = tid >> 7;
      float a = 0.f;
      if (c < D) {
#pragma unroll 8
        for (int k = ks * 32; k < ks * 32 + 32; ++k) a += res1_l[k] * Wo[k * D + c];
      }
      scr[ks * 128 + c] = a;
    }
    __syncthreads();
    if (tid < D) {
      float dv = bo[tid];
#pragma unroll
      for (int ks = 0; ks < 8; ++ks) dv += scr[ks * 128 + tid];
      const size_t base = (size_t)t * RF * (B * D) + (size_t)b * D + tid;
#pragma unroll
      for (int i = 0; i < RF; ++i)
        __builtin_nontemporal_store(dv, &dout[base + (size_t)i * (B * D)]);
    }
    __syncthreads();
  }
}

// ---------------------------------------------------------------------------
extern "C" void kernel_launch(void* const* d_in, const int* in_sizes, int n_in,
                              void* d_out, int out_size, void* d_ws,
                              size_t ws_size, hipStream_t stream) {
  const float* outs   = (const float*)d_in[0];
  const float* memory = (const float*)d_in[1];
  const float* Wp0    = (const float*)d_in[2];
  const float* bp0    = (const float*)d_in[3];
  const float* Wp1    = (const float*)d_in[4];
  const float* bp1    = (const float*)d_in[5];
  const float* Wx_att = (const float*)d_in[6];
  const float* Wh_att = (const float*)d_in[7];
  const float* b_att  = (const float*)d_in[8];
  const float* Wq     = (const float*)d_in[9];
  const float* Wm     = (const float*)d_in[10];
  const float* v_att  = (const float*)d_in[11];
  const float* Wx_d0  = (const float*)d_in[12];
  const float* Wh_d0  = (const float*)d_in[13];
  const float* b_d0   = (const float*)d_in[14];
  const float* Wx_d1  = (const float*)d_in[15];
  const float* Wh_d1  = (const float*)d_in[16];
  const float* b_d1   = (const float*)d_in[17];
  const float* Wo     = (const float*)d_in[18];
  const float* bo     = (const float*)d_in[19];
  float* dout = (float*)d_out;
  float* wsf  = (float*)d_ws;

  float* keys = wsf;                              // 16.78M floats
  float* pre  = wsf + (size_t)TIN * B * H;        // 3.28M floats

  k_keys<<<(TIN * B) / 32, 256, 0, stream>>>(memory, Wm, keys);
  k_prenet<<<RSTEPS * B, 256, 0, stream>>>(outs, Wp0, bp0, Wp1, bp1, pre);

  float* alpha = dout + (size_t)1000 * B * D;
  k_step<<<B, 1024, 0, stream>>>(memory, keys, pre,
                                 Wx_att, Wh_att, b_att, Wq, v_att,
                                 Wx_d0, Wh_d0, b_d0, Wx_d1, Wh_d1, b_d1,
                                 Wo, bo, dout, alpha);
}

// Round 6
// 23045.189 us; speedup vs baseline: 7.1066x; 1.9477x over previous
//
#include <hip/hip_runtime.h>

namespace {
constexpr int B = 128;      // batch
constexpr int D = 80;       // mel dim
constexpr int H = 256;      // hidden
constexpr int PP = 128;     // prenet out
constexpr int TIN = 512;    // encoder steps
constexpr int RSTEPS = 200; // reduced steps
constexpr int RF = 5;       // reduction factor
}

__device__ __forceinline__ float sigm(float x) { return 1.f / (1.f + __expf(-x)); }
__device__ __forceinline__ float tanh_(float x) { return 1.f - 2.f / (__expf(2.f * x) + 1.f); }
__device__ __forceinline__ float dot4(float4 a, float4 b) {
  return a.x * b.x + a.y * b.y + a.z * b.z + a.w * b.w;
}

// ---------------------------------------------------------------------------
// keysT[b,t,k] = sum_h memory[t,b,h] * Wm[h,k]  (transposed store: contiguous per b)
__global__ __launch_bounds__(256) void k_keys(const float* __restrict__ mem,
                                              const float* __restrict__ Wm,
                                              float* __restrict__ keysT) {
  const int k = threadIdx.x;
  const int m0 = blockIdx.x * 32;
  const float* xb = mem + (size_t)m0 * H;
  float acc[32];
#pragma unroll
  for (int i = 0; i < 32; ++i) acc[i] = 0.f;
  for (int h = 0; h < H; h += 4) {
    const float w0 = Wm[(h + 0) * H + k];
    const float w1 = Wm[(h + 1) * H + k];
    const float w2 = Wm[(h + 2) * H + k];
    const float w3 = Wm[(h + 3) * H + k];
#pragma unroll
    for (int mi = 0; mi < 32; ++mi) {
      const float4 x = *reinterpret_cast<const float4*>(xb + (size_t)mi * H + h);
      acc[mi] += x.x * w0 + x.y * w1 + x.z * w2 + x.w * w3;
    }
  }
#pragma unroll
  for (int mi = 0; mi < 32; ++mi) {
    const int m = m0 + mi, t = m >> 7, bb = m & 127;
    keysT[((size_t)bb * TIN + t) * H + k] = acc[mi];
  }
}

// memT[b,t,h] = memory[t,b,h]
__global__ __launch_bounds__(256) void k_memT(const float* __restrict__ mem,
                                              float* __restrict__ memT) {
  const int m = blockIdx.x, t = m >> 7, bb = m & 127;
  memT[((size_t)bb * TIN + t) * H + threadIdx.x] = mem[(size_t)m * H + threadIdx.x];
}

// pack W[K][C] -> Wp[(k>>2)*C + c][k&3]  (float4 of 4 consecutive k per col)
__global__ __launch_bounds__(256) void k_pack4(const float* __restrict__ W,
                                               float* __restrict__ Wp, int K, int C) {
  const int idx = blockIdx.x * 256 + threadIdx.x;
  if (idx >= K * C) return;
  const int k = idx / C, c = idx - k * C;
  Wp[((size_t)(k >> 2) * C + c) * 4 + (k & 3)] = W[idx];
}

// ---------------------------------------------------------------------------
// Hoisted prenet (teacher-forced frames come from INPUT outs).
__global__ __launch_bounds__(256) void k_prenet(
    const float* __restrict__ outs, const float* __restrict__ Wp0,
    const float* __restrict__ bp0, const float* __restrict__ Wp1,
    const float* __restrict__ bp1, float* __restrict__ pre) {
  const int t = blockIdx.x >> 7, b = blockIdx.x & 127, tid = threadIdx.x;
  __shared__ float f[80];
  __shared__ float p0[256];
  __shared__ float s2[256];
  if (tid < 80)
    f[tid] = (t == 0) ? 0.f
                      : __builtin_nontemporal_load(
                            &outs[((size_t)(t * RF - 1) * B + b) * D + tid]);
  __syncthreads();
  {
    float a = bp0[tid];
#pragma unroll 8
    for (int k = 0; k < 80; ++k) a += f[k] * Wp0[k * 256 + tid];
    p0[tid] = fmaxf(a, 0.f);
  }
  __syncthreads();
  {
    const int c = tid & 127, kh = tid >> 7;
    float a = 0.f;
#pragma unroll 8
    for (int k = kh * 128; k < kh * 128 + 128; ++k) a += p0[k] * Wp1[k * 128 + c];
    s2[kh * 128 + c] = a;
  }
  __syncthreads();
  if (tid < 128)
    pre[((size_t)t * B + b) * PP + tid] = fmaxf(bp1[tid] + s2[tid] + s2[128 + tid], 0.f);
}

// ---------------------------------------------------------------------------
// Persistent per-batch-row block; float4 packed-weight GEMVs, float4 streams.
__global__ __launch_bounds__(1024, 4) void k_step(
    const float* __restrict__ memT, const float* __restrict__ keysT,
    const float* __restrict__ pre,
    const float* __restrict__ wxa4, const float* __restrict__ wha4,
    const float* __restrict__ b_att, const float* __restrict__ wq4,
    const float* __restrict__ v_att,
    const float* __restrict__ wxd04, const float* __restrict__ whd04,
    const float* __restrict__ b_d0,
    const float* __restrict__ wxd14, const float* __restrict__ whd14,
    const float* __restrict__ b_d1,
    const float* __restrict__ Wo, const float* __restrict__ bo,
    float* __restrict__ dout, float* __restrict__ alpha) {
  const int b = blockIdx.x;
  const int tid = threadIdx.x;
  const int lane = tid & 63, wv = tid >> 6;

  __shared__ alignas(16) float hA[256], hD0[256], hD1[256];
  __shared__ alignas(16) float qk_l[256], ctx_l[256], res0_l[256], res1_l[256];
  __shared__ alignas(16) float pre_l[128];
  __shared__ alignas(16) float v_l[256];
  __shared__ alignas(16) float scr[4096];
  __shared__ alignas(16) float ep[512];
  __shared__ float r16[16];
  __shared__ float bc[2];

  if (tid < 256) { hA[tid] = 0.f; hD0[tid] = 0.f; hD1[tid] = 0.f; v_l[tid] = v_att[tid]; }
  __syncthreads();

  const float4* hA4 = reinterpret_cast<const float4*>(hA);
  const float4* hD04 = reinterpret_cast<const float4*>(hD0);
  const float4* hD14 = reinterpret_cast<const float4*>(hD1);
  const float4* ctx4 = reinterpret_cast<const float4*>(ctx_l);
  const float4* res04 = reinterpret_cast<const float4*>(res0_l);
  const float4* pre4 = reinterpret_cast<const float4*>(pre_l);
  const float4* qk4 = reinterpret_cast<const float4*>(qk_l);
  const float4* v4 = reinterpret_cast<const float4*>(v_l);
  float4* scr4 = reinterpret_cast<float4*>(scr);

  for (int t = 0; t < RSTEPS; ++t) {
    if (tid < PP) pre_l[tid] = pre[((size_t)t * B + b) * PP + tid];
    __syncthreads();

    // ---- attention GRU: x-part (K=128) + h-part (K=256), packed float4 ----
    {
      const int j = tid & 255, ks = tid >> 8;   // 4 K-slices
      float pz = 0, pr = 0, px = 0, ph = 0;
#pragma unroll 4
      for (int kq = ks * 8; kq < ks * 8 + 8; ++kq) {       // x: 32 k-quads
        const float4 xv = pre4[kq];
        const float4* wr = reinterpret_cast<const float4*>(wxa4) + (size_t)kq * 768;
        pz += dot4(wr[j], xv); pr += dot4(wr[256 + j], xv); px += dot4(wr[512 + j], xv);
      }
#pragma unroll 4
      for (int kq = ks * 16; kq < ks * 16 + 16; ++kq) {    // h: 64 k-quads
        const float4 hv = hA4[kq];
        const float4* wr = reinterpret_cast<const float4*>(wha4) + (size_t)kq * 768;
        pz += dot4(wr[j], hv); pr += dot4(wr[256 + j], hv); ph += dot4(wr[512 + j], hv);
      }
      scr[ks * 1024 + j] = pz;       scr[ks * 1024 + 256 + j] = pr;
      scr[ks * 1024 + 512 + j] = px; scr[ks * 1024 + 768 + j] = ph;
    }
    __syncthreads();
    if (tid < 256) {
      float az = 0, ar = 0, acx = 0, ach = 0;
#pragma unroll
      for (int ks = 0; ks < 4; ++ks) {
        az += scr[ks * 1024 + tid];        ar += scr[ks * 1024 + 256 + tid];
        acx += scr[ks * 1024 + 512 + tid]; ach += scr[ks * 1024 + 768 + tid];
      }
      const float z = sigm(az + b_att[tid]);
      const float r = sigm(ar + b_att[256 + tid]);
      const float c = tanh_(acx + r * ach + b_att[512 + tid]);
      hA[tid] = (1.f - z) * hA[tid] + z * c;   // = query
    }
    __syncthreads();

    // ---- qW (K=256, 256 cols, packed) ----
    {
      const int c = tid & 255, ks = tid >> 8;
      float a = 0.f;
#pragma unroll 4
      for (int kq = ks * 16; kq < ks * 16 + 16; ++kq) {
        const float4 hv = hA4[kq];
        a += dot4(reinterpret_cast<const float4*>(wq4)[(size_t)kq * 256 + c], hv);
      }
      scr[ks * 256 + c] = a;
    }
    __syncthreads();
    if (tid < 256)
      qk_l[tid] = scr[tid] + scr[256 + tid] + scr[512 + tid] + scr[768 + tid];
    __syncthreads();

    // ---- e-pass: 64 groups x 16 lanes, float4 keys, 2 t-rows in flight ----
    {
      const int l16 = tid & 15, g = tid >> 4;
      float4 qg[4], vg[4];
#pragma unroll
      for (int i = 0; i < 4; ++i) { qg[i] = qk4[l16 + 16 * i]; vg[i] = v4[l16 + 16 * i]; }
      const float4* kT = reinterpret_cast<const float4*>(keysT + (size_t)b * TIN * H);
#pragma unroll
      for (int p = 0; p < 4; ++p) {
        const int t1 = g + p * 128, t2 = t1 + 64;
        const float4* k1 = kT + (size_t)t1 * 64;
        const float4* k2 = kT + (size_t)t2 * 64;
        float s1 = 0.f, s2 = 0.f;
#pragma unroll
        for (int i = 0; i < 4; ++i) {
          const float4 a1 = k1[l16 + 16 * i], a2 = k2[l16 + 16 * i];
          s1 += vg[i].x * tanh_(a1.x + qg[i].x) + vg[i].y * tanh_(a1.y + qg[i].y) +
                vg[i].z * tanh_(a1.z + qg[i].z) + vg[i].w * tanh_(a1.w + qg[i].w);
          s2 += vg[i].x * tanh_(a2.x + qg[i].x) + vg[i].y * tanh_(a2.y + qg[i].y) +
                vg[i].z * tanh_(a2.z + qg[i].z) + vg[i].w * tanh_(a2.w + qg[i].w);
        }
#pragma unroll
        for (int m = 1; m < 16; m <<= 1) { s1 += __shfl_xor(s1, m, 16); s2 += __shfl_xor(s2, m, 16); }
        if (l16 == 0) { ep[t1] = s1; ep[t2] = s2; }
      }
    }
    __syncthreads();

    // ---- softmax over 512 ----
    float ev = -1e30f, pv = 0.f;
    if (tid < TIN) {
      ev = ep[tid];
      float mx = ev;
#pragma unroll
      for (int m = 1; m < 64; m <<= 1) mx = fmaxf(mx, __shfl_xor(mx, m));
      if (lane == 0) r16[wv] = mx;
    }
    __syncthreads();
    if (tid == 0) {
      float g = r16[0];
#pragma unroll
      for (int w = 1; w < 8; ++w) g = fmaxf(g, r16[w]);
      bc[0] = g;
    }
    __syncthreads();
    const float M = bc[0];
    if (tid < TIN) {
      pv = __expf(ev - M);
      ep[tid] = pv;
      float s = pv;
#pragma unroll
      for (int m = 1; m < 64; m <<= 1) s += __shfl_xor(s, m);
      if (lane == 0) r16[wv] = s;
    }
    __syncthreads();
    if (tid == 0) {
      float s = 0.f;
#pragma unroll
      for (int w = 0; w < 8; ++w) s += r16[w];
      bc[1] = 1.f / s;
    }
    __syncthreads();
    const float inv = bc[1];
    if (tid < TIN)
      __builtin_nontemporal_store(pv * inv, &alpha[((size_t)t * B + b) * TIN + tid]);

    // ---- context: float4 memT, 64 k-quads x 16 t-slices ----
    {
      const int kq = tid & 63, ts = tid >> 6;
      float4 a = {0.f, 0.f, 0.f, 0.f};
      const float4* mT = reinterpret_cast<const float4*>(memT + (size_t)b * TIN * H);
#pragma unroll 8
      for (int i = 0; i < 32; ++i) {
        const int tt = ts * 32 + i;
        const float p = ep[tt];
        const float4 m = mT[(size_t)tt * 64 + kq];
        a.x += p * m.x; a.y += p * m.y; a.z += p * m.z; a.w += p * m.w;
      }
      scr4[ts * 64 + kq] = a;
    }
    __syncthreads();
    if (tid < 256) {
      const int quad = tid >> 2, sub = tid & 3;
      float s = 0.f;
#pragma unroll
      for (int ts = 0; ts < 16; ++ts) s += scr[(ts * 64 + quad) * 4 + sub];
      ctx_l[tid] = inv * s;
    }
    __syncthreads();

    // ---- decoder GRU 0: x=[query;ctx] (K=512) + h (K=256), packed ----
    {
      const int j = tid & 255, ks = tid >> 8;
      float pz = 0, pr = 0, px = 0, ph = 0;
#pragma unroll 4
      for (int kq = ks * 32; kq < ks * 32 + 32; ++kq) {    // x: 128 k-quads
        const float4 xv = (kq < 64) ? hA4[kq] : ctx4[kq - 64];
        const float4* wr = reinterpret_cast<const float4*>(wxd04) + (size_t)kq * 768;
        pz += dot4(wr[j], xv); pr += dot4(wr[256 + j], xv); px += dot4(wr[512 + j], xv);
      }
#pragma unroll 4
      for (int kq = ks * 16; kq < ks * 16 + 16; ++kq) {    // h: 64 k-quads
        const float4 hv = hD04[kq];
        const float4* wr = reinterpret_cast<const float4*>(whd04) + (size_t)kq * 768;
        pz += dot4(wr[j], hv); pr += dot4(wr[256 + j], hv); ph += dot4(wr[512 + j], hv);
      }
      scr[ks * 1024 + j] = pz;       scr[ks * 1024 + 256 + j] = pr;
      scr[ks * 1024 + 512 + j] = px; scr[ks * 1024 + 768 + j] = ph;
    }
    __syncthreads();
    if (tid < 256) {
      float az = 0, ar = 0, acx = 0, ach = 0;
#pragma unroll
      for (int ks = 0; ks < 4; ++ks) {
        az += scr[ks * 1024 + tid];        ar += scr[ks * 1024 + 256 + tid];
        acx += scr[ks * 1024 + 512 + tid]; ach += scr[ks * 1024 + 768 + tid];
      }
      const float z = sigm(az + b_d0[tid]);
      const float r = sigm(ar + b_d0[256 + tid]);
      const float c = tanh_(acx + r * ach + b_d0[512 + tid]);
      const float hn = (1.f - z) * hD0[tid] + z * c;
      hD0[tid] = hn;
      res0_l[tid] = hA[tid] + hn;
    }
    __syncthreads();

    // ---- decoder GRU 1: x=res0 (K=256) + h (K=256), packed ----
    {
      const int j = tid & 255, ks = tid >> 8;
      float pz = 0, pr = 0, px = 0, ph = 0;
#pragma unroll 4
      for (int kq = ks * 16; kq < ks * 16 + 16; ++kq) {
        const float4 xv = res04[kq];
        const float4* wr = reinterpret_cast<const float4*>(wxd14) + (size_t)kq * 768;
        pz += dot4(wr[j], xv); pr += dot4(wr[256 + j], xv); px += dot4(wr[512 + j], xv);
      }
#pragma unroll 4
      for (int kq = ks * 16; kq < ks * 16 + 16; ++kq) {
        const float4 hv = hD14[kq];
        const float4* wr = reinterpret_cast<const float4*>(whd14) + (size_t)kq * 768;
        pz += dot4(wr[j], hv); pr += dot4(wr[256 + j], hv); ph += dot4(wr[512 + j], hv);
      }
      scr[ks * 1024 + j] = pz;       scr[ks * 1024 + 256 + j] = pr;
      scr[ks * 1024 + 512 + j] = px; scr[ks * 1024 + 768 + j] = ph;
    }
    __syncthreads();
    if (tid < 256) {
      float az = 0, ar = 0, acx = 0, ach = 0;
#pragma unroll
      for (int ks = 0; ks < 4; ++ks) {
        az += scr[ks * 1024 + tid];        ar += scr[ks * 1024 + 256 + tid];
        acx += scr[ks * 1024 + 512 + tid]; ach += scr[ks * 1024 + 768 + tid];
      }
      const float z = sigm(az + b_d1[tid]);
      const float r = sigm(ar + b_d1[256 + tid]);
      const float c = tanh_(acx + r * ach + b_d1[512 + tid]);
      const float hn = (1.f - z) * hD1[tid] + z * c;
      hD1[tid] = hn;
      res1_l[tid] = res0_l[tid] + hn;
    }
    __syncthreads();

    // ---- dense: 80 cols, 8 K-slices -> 5 output frames (NT) ----
    {
      const int c = tid & 127, ks = tid >> 7;
      float a = 0.f;
      if (c < D) {
#pragma unroll 8
        for (int k = ks * 32; k < ks * 32 + 32; ++k) a += res1_l[k] * Wo[k * D + c];
      }
      scr[ks * 128 + c] = a;
    }
    __syncthreads();
    if (tid < D) {
      float dv = bo[tid];
#pragma unroll
      for (int ks = 0; ks < 8; ++ks) dv += scr[ks * 128 + tid];
      const size_t base = (size_t)t * RF * (B * D) + (size_t)b * D + tid;
#pragma unroll
      for (int i = 0; i < RF; ++i)
        __builtin_nontemporal_store(dv, &dout[base + (size_t)i * (B * D)]);
    }
    __syncthreads();
  }
}

// ---------------------------------------------------------------------------
extern "C" void kernel_launch(void* const* d_in, const int* in_sizes, int n_in,
                              void* d_out, int out_size, void* d_ws,
                              size_t ws_size, hipStream_t stream) {
  const float* outs   = (const float*)d_in[0];
  const float* memory = (const float*)d_in[1];
  const float* Wp0    = (const float*)d_in[2];
  const float* bp0    = (const float*)d_in[3];
  const float* Wp1    = (const float*)d_in[4];
  const float* bp1    = (const float*)d_in[5];
  const float* Wx_att = (const float*)d_in[6];
  const float* Wh_att = (const float*)d_in[7];
  const float* b_att  = (const float*)d_in[8];
  const float* Wq     = (const float*)d_in[9];
  const float* Wm     = (const float*)d_in[10];
  const float* v_att  = (const float*)d_in[11];
  const float* Wx_d0  = (const float*)d_in[12];
  const float* Wh_d0  = (const float*)d_in[13];
  const float* b_d0   = (const float*)d_in[14];
  const float* Wx_d1  = (const float*)d_in[15];
  const float* Wh_d1  = (const float*)d_in[16];
  const float* b_d1   = (const float*)d_in[17];
  const float* Wo     = (const float*)d_in[18];
  const float* bo     = (const float*)d_in[19];
  float* dout = (float*)d_out;
  float* wsf  = (float*)d_ws;

  size_t off = 0;
  float* keysT = wsf + off; off += (size_t)TIN * B * H;   // 16.78M
  float* memT  = wsf + off; off += (size_t)TIN * B * H;   // 16.78M
  float* pre   = wsf + off; off += (size_t)RSTEPS * B * PP;
  float* wxa4  = wsf + off; off += (size_t)128 * 768;
  float* wha4  = wsf + off; off += (size_t)256 * 768;
  float* wq4   = wsf + off; off += (size_t)256 * 256;
  float* wxd04 = wsf + off; off += (size_t)512 * 768;
  float* whd04 = wsf + off; off += (size_t)256 * 768;
  float* wxd14 = wsf + off; off += (size_t)256 * 768;
  float* whd14 = wsf + off; off += (size_t)256 * 768;

  k_keys<<<(TIN * B) / 32, 256, 0, stream>>>(memory, Wm, keysT);
  k_memT<<<TIN * B, 256, 0, stream>>>(memory, memT);
  k_prenet<<<RSTEPS * B, 256, 0, stream>>>(outs, Wp0, bp0, Wp1, bp1, pre);
  k_pack4<<<(128 * 768 + 255) / 256, 256, 0, stream>>>(Wx_att, wxa4, 128, 768);
  k_pack4<<<(256 * 768 + 255) / 256, 256, 0, stream>>>(Wh_att, wha4, 256, 768);
  k_pack4<<<(256 * 256 + 255) / 256, 256, 0, stream>>>(Wq, wq4, 256, 256);
  k_pack4<<<(512 * 768 + 255) / 256, 256, 0, stream>>>(Wx_d0, wxd04, 512, 768);
  k_pack4<<<(256 * 768 + 255) / 256, 256, 0, stream>>>(Wh_d0, whd04, 256, 768);
  k_pack4<<<(256 * 768 + 255) / 256, 256, 0, stream>>>(Wx_d1, wxd14, 256, 768);
  k_pack4<<<(256 * 768 + 255) / 256, 256, 0, stream>>>(Wh_d1, whd14, 256, 768);

  float* alpha = dout + (size_t)1000 * B * D;
  k_step<<<B, 1024, 0, stream>>>(memT, keysT, pre,
                                 wxa4, wha4, b_att, wq4, v_att,
                                 wxd04, whd04, b_d0, wxd14, whd14, b_d1,
                                 Wo, bo, dout, alpha);
}